// Round 15
// baseline (50554.904 us; speedup 1.0000x reference)
//
#include <hip/hip_runtime.h>
#include <math.h>

#define Gz   250
#define NTz  512
#define Bz   32
#define Hz   512
#define Vz   32000
#define Tz   128
#define VBz  128
#define BHz  (Bz*Hz)
#define LBHz (2*BHz)
#define BTVz ((size_t)Bz*(size_t)Tz*(size_t)Vz)

// per-instance workspace byte offsets
#define WS_BAR  0         // unsigned[512]
#define WS_ASUM 2048      // float[64][32]
#define WS_AMAX 10240     // ull[64][32]
#define WS_H    26624     // float[2 parity][2 layer][32][512]
#define INST_B  327680
#define NINST   4

// LDS byte offsets (dynamic)
#define L_HSA    0
#define L_HSB    65536
#define L_LOGITS 131072
#define L_SPART  131072
#define L_PMAX   147584
#define L_PSUM   151680
#define L_REDM   153728
#define L_REDS   155776
#define L_BIAS   156800
#define L_LOGZ   156864
#define L_TOK    156992
#define L_C      157120
#define L_TOTAL  158144

typedef unsigned long long ull;
typedef float f32x4 __attribute__((ext_vector_type(4)));

__device__ __forceinline__ float sigmf(float x) { return 1.0f / (1.0f + expf(-x)); }

__device__ __forceinline__ ull bp8(const float* p) {
  return __hip_atomic_load((const ull*)p, __ATOMIC_RELAXED, __HIP_MEMORY_SCOPE_AGENT);
}
__device__ __forceinline__ void cstore(float* p, float v) {
  __hip_atomic_store(p, v, __ATOMIC_RELAXED, __HIP_MEMORY_SCOPE_AGENT);
}
__device__ __forceinline__ ull packlm(float x, int v) {
  unsigned u = __float_as_uint(x);
  u = (u & 0x80000000u) ? ~u : (u | 0x80000000u);
  return ((ull)u << 32) | (unsigned)(Vz - 1 - v);
}
__device__ __forceinline__ int hoff(int b, int k) { return (b << 9) + (k ^ ((b & 15) << 2)); }

__device__ __forceinline__ void grid_barrier(unsigned* bar, int bid) {
  __syncthreads();
  if (threadIdx.x == 0) {
    unsigned* gen = bar + 257;
    unsigned g = __hip_atomic_load(gen, __ATOMIC_RELAXED, __HIP_MEMORY_SCOPE_AGENT);
    const int gi = bid & 7;
    const unsigned gsz = (unsigned)(Gz >> 3) + (((unsigned)gi < (Gz & 7u)) ? 1u : 0u);
    unsigned prev = __hip_atomic_fetch_add(&bar[gi * 32], 1u, __ATOMIC_RELAXED, __HIP_MEMORY_SCOPE_AGENT);
    if (prev == gsz - 1u) {
      __hip_atomic_store(&bar[gi * 32], 0u, __ATOMIC_RELAXED, __HIP_MEMORY_SCOPE_AGENT);
      asm volatile("s_waitcnt vmcnt(0)" ::: "memory");
      unsigned pm = __hip_atomic_fetch_add(&bar[256], 1u, __ATOMIC_RELAXED, __HIP_MEMORY_SCOPE_AGENT);
      if (pm == 7u) {
        __hip_atomic_store(&bar[256], 0u, __ATOMIC_RELAXED, __HIP_MEMORY_SCOPE_AGENT);
        asm volatile("s_waitcnt vmcnt(0)" ::: "memory");
        __hip_atomic_store(gen, g + 1u, __ATOMIC_RELAXED, __HIP_MEMORY_SCOPE_AGENT);
      }
    }
    while (__hip_atomic_load(gen, __ATOMIC_RELAXED, __HIP_MEMORY_SCOPE_AGENT) == g)
      __builtin_amdgcn_s_sleep(1);
  }
  __syncthreads();
}

__device__ __forceinline__ void stage_rows(const float* __restrict__ src, float* lds, int tid) {
  #pragma unroll
  for (int it = 0; it < 16; ++it) {
    int f = (it * NTz + tid) << 1;
    int b = f >> 9, k = f & 511;
    ull v = bp8(src + f);
    *(ull*)(lds + hoff(b, k)) = v;
  }
}

template<bool X_FROM_EMB>
__device__ __forceinline__ void lstm_phase(
    int tid, int hblk,
    const float* __restrict__ emb, const int* s_tok_,
    const float* xlds, const float* hlds,
    const float* __restrict__ Wih, const float* __restrict__ Whh,
    const float* __restrict__ bih, const float* __restrict__ bhh,
    float* s_part_, float* s_bias_, float* c_l,
    float* hdst)
{
  if (tid < 16) {
    int gate = tid >> 2, hl = tid & 3;
    int j = gate * Hz + (hblk << 2) + hl;
    s_bias_[tid] = bih[j] + bhh[j];
  }
  const int b = tid & 31, kq = (tid >> 5) & 7, rp = tid >> 8;
  const int k0 = kq * 64;
  const int swz = (b & 15) << 2;

  const float* wiA = Wih + (size_t)(2 * rp * Hz + (hblk << 2)) * Hz + k0;
  const float* whA = Whh + (size_t)(2 * rp * Hz + (hblk << 2)) * Hz + k0;

  const float* xbase; const float* hbase = hlds + (b << 9);
  if (X_FROM_EMB) xbase = emb + (size_t)s_tok_[b] * Hz + k0;
  else            xbase = xlds + (b << 9);

  float acc[8];
  #pragma unroll
  for (int r = 0; r < 8; ++r) acc[r] = 0.f;

  #pragma unroll 2
  for (int c = 0; c < 64; c += 4) {
    float x0, x1, x2, x3;
    if (X_FROM_EMB) {
      float4 xv = *(const float4*)(xbase + c);
      x0 = fmaxf(xv.x, 0.f); x1 = fmaxf(xv.y, 0.f);
      x2 = fmaxf(xv.z, 0.f); x3 = fmaxf(xv.w, 0.f);
    } else {
      float4 xv = *(const float4*)(xbase + ((k0 + c) ^ swz));
      x0 = xv.x; x1 = xv.y; x2 = xv.z; x3 = xv.w;
    }
    float4 hv = *(const float4*)(hbase + ((k0 + c) ^ swz));
    #pragma unroll
    for (int r = 0; r < 8; ++r) {
      const size_t off = (size_t)(r >> 2) * (Hz * Hz) + (size_t)(r & 3) * Hz + c;
      float4 wiv = *(const float4*)(wiA + off);
      float4 whv = *(const float4*)(whA + off);
      acc[r] += x0 * wiv.x + x1 * wiv.y + x2 * wiv.z + x3 * wiv.w
              + hv.x * whv.x + hv.y * whv.y + hv.z * whv.z + hv.w * whv.w;
    }
  }
  #pragma unroll
  for (int r = 0; r < 8; ++r)
    s_part_[((rp * 8 + r) * 32 + b) * 8 + kq] = acc[r];
  __syncthreads();
  {
    int row = tid >> 5, bb = tid & 31;
    float s = s_bias_[row];
    #pragma unroll
    for (int q = 0; q < 8; ++q) s += s_part_[(row * 32 + bb) * 8 + q];
    s_part_[(row * 32 + bb) * 8] = s;
  }
  __syncthreads();
  if (tid < 128) {
    int hl = tid >> 5, bb = tid & 31;
    float gi = s_part_[((0 * 4 + hl) * 32 + bb) * 8];
    float gf = s_part_[((1 * 4 + hl) * 32 + bb) * 8];
    float gg = s_part_[((2 * 4 + hl) * 32 + bb) * 8];
    float go = s_part_[((3 * 4 + hl) * 32 + bb) * 8];
    float c_old = c_l[hl * 32 + bb];
    float cn = sigmf(gf) * c_old + sigmf(gi) * tanhf(gg);
    c_l[hl * 32 + bb] = cn;
    cstore(hdst + bb * Hz + (hblk << 2) + hl, sigmf(go) * tanhf(cn));
  }
}

__device__ __forceinline__ void tok_reduce(int tid, float* acc_sum, ull* acc_max,
                                           float* redS, ull* redM, float* logZ, int* tok) {
  if (tid < 256) {
    int b = tid & 31, g = tid >> 5;
    float s = 0.f; ull m = 0ull;
    #pragma unroll
    for (int u = 0; u < 8; ++u) {
      int bk = g * 8 + u;
      s += __hip_atomic_load(&acc_sum[bk * Bz + b], __ATOMIC_RELAXED, __HIP_MEMORY_SCOPE_AGENT);
      ull x = __hip_atomic_load(&acc_max[bk * Bz + b], __ATOMIC_RELAXED, __HIP_MEMORY_SCOPE_AGENT);
      m = x > m ? x : m;
    }
    redS[g * Bz + b] = s; redM[g * Bz + b] = m;
  }
  __syncthreads();
  if (tid < 32) {
    float s = 0.f; ull m = 0ull;
    #pragma unroll
    for (int g = 0; g < 8; ++g) {
      s += redS[g * Bz + tid];
      ull x = redM[g * Bz + tid]; m = x > m ? x : m;
    }
    logZ[tid] = logf(s);
    int tk = (Vz - 1) - (int)(unsigned)(m & 0xFFFFFFFFull);
    tok[tid] = tk < 0 ? 0 : (tk > Vz - 1 ? Vz - 1 : tk);
  }
  __syncthreads();
}

__device__ __forceinline__ void write_logp(int tid, int v0, int tstep,
                                           const float* logits_, const float* logZ_, float* out) {
  #pragma unroll
  for (int i = 0; i < 2; ++i) {
    int pos = ((i * NTz) + tid) * 4;
    int b = pos >> 7, v = pos & 127;
    float lz = logZ_[b];
    f32x4 rr;
    rr.x = logits_[b * 129 + v]     - lz;
    rr.y = logits_[b * 129 + v + 1] - lz;
    rr.z = logits_[b * 129 + v + 2] - lz;
    rr.w = logits_[b * 129 + v + 3] - lz;
    __builtin_nontemporal_store(rr,
        (f32x4*)(out + (size_t)b * ((size_t)Tz * Vz) + (size_t)tstep * Vz + v0 + v));
  }
}

__global__ void rnn_init(const float* __restrict__ enc, float* __restrict__ ws) {
  int i = blockIdx.x * blockDim.x + threadIdx.x;
  float* hs = (float*)((char*)ws + WS_H);
  if (i < LBHz) hs[i] = enc[i];
  if (i < 2048) {
    ((float*)((char*)ws + WS_ASUM))[i] = 0.f;
    ((ull*)((char*)ws + WS_AMAX))[i] = 0ull;
  }
  if (i < 512) ((unsigned*)ws)[i] = 0u;
}

#define WL(r, J) (*(const f32x4*)(wr##r + (((J + kq) & 7) << 2)))
#define P3J(J) { \
  const int kk = (kq << 5) + (((J + kq) & 7) << 2); \
  f32x4 h4 = *(const f32x4*)(hb + (kk ^ swz)); \
  a0 += h4 * w0##J; a1 += h4 * w1##J; a2 += h4 * w2##J; a3 += h4 * w3##J; }

// MODE: 0 = no-matvec (bias logits, const buckets, no out)
//       1 = +matvec (const buckets, no out)
//       2 = +softmax scan/buckets (no out)
//       3 = full (write_logp + epilogue)
template<int MODE>
__device__ __forceinline__ void decode_body(
    const float* __restrict__ emb,  const float* __restrict__ Wih,
    const float* __restrict__ Whh,  const float* __restrict__ bih,
    const float* __restrict__ bhh,  const float* __restrict__ Wout,
    const float* __restrict__ bout, float* __restrict__ out,
    float* __restrict__ ws)
{
  extern __shared__ char smem[];
  const int tid = threadIdx.x;
  const int bid = blockIdx.x;

  unsigned* bar  = (unsigned*)ws;
  float* acc_sum = (float*)((char*)ws + WS_ASUM);
  ull*   acc_max = (ull*)((char*)ws + WS_AMAX);
  float* hbufs   = (float*)((char*)ws + WS_H);

  float* hsA    = (float*)(smem + L_HSA);
  float* hsB    = (float*)(smem + L_HSB);
  float* logits = (float*)(smem + L_LOGITS);
  float* s_part = (float*)(smem + L_SPART);
  ull*   pmax   = (ull*)(smem + L_PMAX);
  float* psum   = (float*)(smem + L_PSUM);
  ull*   redM   = (ull*)(smem + L_REDM);
  float* redS   = (float*)(smem + L_REDS);
  float* s_bias = (float*)(smem + L_BIAS);
  float* s_logZ = (float*)(smem + L_LOGZ);
  int*   s_tok  = (int*)(smem + L_TOK);
  float* s_c    = (float*)(smem + L_C);

  const int v0 = bid * VBz;
  if (tid < 256) s_c[tid] = 0.f;
  __syncthreads();

  const int vg = tid >> 4, kq = tid & 15;
  f32x4 w00, w01, w02, w03, w04, w05, w06, w07;
  f32x4 w10, w11, w12, w13, w14, w15, w16, w17;
  f32x4 w20, w21, w22, w23, w24, w25, w26, w27;
  f32x4 w30, w31, w32, w33, w34, w35, w36, w37;
  {
    const float* wr0 = Wout + (size_t)(v0 + (vg << 2) + 0) * Hz + (kq << 5);
    const float* wr1 = Wout + (size_t)(v0 + (vg << 2) + 1) * Hz + (kq << 5);
    const float* wr2 = Wout + (size_t)(v0 + (vg << 2) + 2) * Hz + (kq << 5);
    const float* wr3 = Wout + (size_t)(v0 + (vg << 2) + 3) * Hz + (kq << 5);
    w00 = WL(0,0); w01 = WL(0,1); w02 = WL(0,2); w03 = WL(0,3);
    w04 = WL(0,4); w05 = WL(0,5); w06 = WL(0,6); w07 = WL(0,7);
    w10 = WL(1,0); w11 = WL(1,1); w12 = WL(1,2); w13 = WL(1,3);
    w14 = WL(1,4); w15 = WL(1,5); w16 = WL(1,6); w17 = WL(1,7);
    w20 = WL(2,0); w21 = WL(2,1); w22 = WL(2,2); w23 = WL(2,3);
    w24 = WL(2,4); w25 = WL(2,5); w26 = WL(2,6); w27 = WL(2,7);
    w30 = WL(3,0); w31 = WL(3,1); w32 = WL(3,2); w33 = WL(3,3);
    w34 = WL(3,4); w35 = WL(3,5); w36 = WL(3,6); w37 = WL(3,7);
  }

  for (int t = 0; t < Tz; ++t) {
    asm volatile("" : "+v"(w00),"+v"(w01),"+v"(w02),"+v"(w03),
                      "+v"(w04),"+v"(w05),"+v"(w06),"+v"(w07));
    asm volatile("" : "+v"(w10),"+v"(w11),"+v"(w12),"+v"(w13),
                      "+v"(w14),"+v"(w15),"+v"(w16),"+v"(w17));
    asm volatile("" : "+v"(w20),"+v"(w21),"+v"(w22),"+v"(w23),
                      "+v"(w24),"+v"(w25),"+v"(w26),"+v"(w27));
    asm volatile("" : "+v"(w30),"+v"(w31),"+v"(w32),"+v"(w33),
                      "+v"(w34),"+v"(w35),"+v"(w36),"+v"(w37));

    float* h_old = hbufs + (t & 1) * LBHz;
    float* h_new = hbufs + ((t + 1) & 1) * LBHz;

    //---- P1 ----
    if (bid < 128) stage_rows(h_old, hsA, tid);
    if (t == 0) {
      if (tid < 32) s_tok[tid] = 1;
    } else {
      tok_reduce(tid, acc_sum, acc_max, redS, redM, s_logZ, s_tok);
      if (MODE == 3) write_logp(tid, v0, t - 1, logits, s_logZ, out);
    }
    __syncthreads();
    if (bid < 128)
      lstm_phase<true>(tid, bid, emb, s_tok, nullptr, hsA,
                       Wih, Whh, bih, bhh, s_part, s_bias, s_c, h_new);
    grid_barrier(bar, bid);

    //---- P2 ----
    if (bid < 128) {
      stage_rows(h_new, hsB, tid);
      stage_rows(h_old + BHz, hsA, tid);
      __syncthreads();
      lstm_phase<false>(tid, bid, nullptr, nullptr, hsB, hsA,
                        Wih + (size_t)2048 * Hz, Whh + (size_t)2048 * Hz,
                        bih + 2048, bhh + 2048, s_part, s_bias, s_c + 128, h_new + BHz);
    } else if (bid == 128) {
      for (int u = tid; u < 2048; u += NTz) {
        __hip_atomic_store(&acc_sum[u], 0.f, __ATOMIC_RELAXED, __HIP_MEMORY_SCOPE_AGENT);
        __hip_atomic_store(&acc_max[u], 0ull, __ATOMIC_RELAXED, __HIP_MEMORY_SCOPE_AGENT);
      }
    }
    grid_barrier(bar, bid);

    //---- P3 ----
    stage_rows(h_new + BHz, hsA, tid);
    __syncthreads();
    {
      const float b_r0 = bout[v0 + (vg << 2)];
      const float b_r1 = bout[v0 + (vg << 2) + 1];
      const float b_r2 = bout[v0 + (vg << 2) + 2];
      const float b_r3 = bout[v0 + (vg << 2) + 3];
      if (MODE >= 1) {
        #pragma unroll 2
        for (int b = 0; b < 32; ++b) {
          const float* hb = hsA + (b << 9);
          const int swz = (b & 15) << 2;
          f32x4 a0 = (f32x4)0.f, a1 = (f32x4)0.f, a2 = (f32x4)0.f, a3 = (f32x4)0.f;
          P3J(0) P3J(1) P3J(2) P3J(3) P3J(4) P3J(5) P3J(6) P3J(7)
          float s0 = (a0.x + a0.y) + (a0.z + a0.w);
          float s1 = (a1.x + a1.y) + (a1.z + a1.w);
          float s2 = (a2.x + a2.y) + (a2.z + a2.w);
          float s3 = (a3.x + a3.y) + (a3.z + a3.w);
          #pragma unroll
          for (int m = 1; m < 16; m <<= 1) {
            s0 += __shfl_xor(s0, m);
            s1 += __shfl_xor(s1, m);
            s2 += __shfl_xor(s2, m);
            s3 += __shfl_xor(s3, m);
          }
          if (kq == 0) {
            logits[b * 129 + (vg << 2)]     = s0 + b_r0;
            logits[b * 129 + (vg << 2) + 1] = s1 + b_r1;
            logits[b * 129 + (vg << 2) + 2] = s2 + b_r2;
            logits[b * 129 + (vg << 2) + 3] = s3 + b_r3;
          }
        }
      } else {
        // MODE 0: bias-only logits (keeps LDS writes, skips matvec)
        if (kq == 0) {
          #pragma unroll 4
          for (int b = 0; b < 32; ++b) {
            logits[b * 129 + (vg << 2)]     = b_r0;
            logits[b * 129 + (vg << 2) + 1] = b_r1;
            logits[b * 129 + (vg << 2) + 2] = b_r2;
            logits[b * 129 + (vg << 2) + 3] = b_r3;
          }
        }
      }
    }
    __syncthreads();
    if (MODE >= 2) {
      const int b2 = tid & 31, ch = tid >> 5;
      float m = -3.0e38f; int argv = 0; float s = 0.f;
      #pragma unroll
      for (int u = 0; u < 8; ++u) {
        int vl = ch * 8 + u;
        float x = logits[b2 * 129 + vl];
        s += expf(x);
        if (x > m) { m = x; argv = vl; }
      }
      pmax[ch * 32 + b2] = packlm(m, v0 + argv);
      psum[ch * 32 + b2] = s;
    }
    __syncthreads();
    if (tid < 32) {
      ull m; float s;
      if (MODE >= 2) {
        m = 0ull; s = 0.f;
        #pragma unroll
        for (int ch = 0; ch < 16; ++ch) {
          ull x = pmax[ch * 32 + tid]; m = x > m ? x : m;
          s += psum[ch * 32 + tid];
        }
      } else {
        m = packlm(0.5f, v0 + tid);   // const partials keep atomic traffic
        s = 8.0f;
      }
      atomicAdd(&acc_sum[(bid & 63) * Bz + tid], s);
      atomicMax(&acc_max[(bid & 63) * Bz + tid], m);
    }
    grid_barrier(bar, bid);
  }

  //---- epilogue (full mode only) ----
  if (MODE == 3) {
    tok_reduce(tid, acc_sum, acc_max, redS, redM, s_logZ, s_tok);
    write_logp(tid, v0, Tz - 1, logits, s_logZ, out);
    if (bid >= 128 && bid < 144) {
      int f = (bid - 128) * 2048 + tid * 4;
      ull a = bp8(hbufs + f), b = bp8(hbufs + f + 2);
      *(ull*)(out + BTVz + f) = a;
      *(ull*)(out + BTVz + f + 2) = b;
    }
    if (bid < 128 && tid < 256) {
      int l = tid >> 7, hl = (tid >> 5) & 3, bb = tid & 31;
      out[BTVz + LBHz + (size_t)l * BHz + (size_t)bb * Hz + (bid << 2) + hl] =
          s_c[l * 128 + hl * 32 + bb];
    }
  }
}

__global__ __launch_bounds__(NTz, 2) void zz_nomv(
    const float* emb, const float* Wih, const float* Whh, const float* bih,
    const float* bhh, const float* Wout, const float* bout, float* out, float* ws)
{ decode_body<0>(emb, Wih, Whh, bih, bhh, Wout, bout, out, ws); }

__global__ __launch_bounds__(NTz, 2) void zz_nosm(
    const float* emb, const float* Wih, const float* Whh, const float* bih,
    const float* bhh, const float* Wout, const float* bout, float* out, float* ws)
{ decode_body<1>(emb, Wih, Whh, bih, bhh, Wout, bout, out, ws); }

__global__ __launch_bounds__(NTz, 2) void zz_nowr(
    const float* emb, const float* Wih, const float* Whh, const float* bih,
    const float* bhh, const float* Wout, const float* bout, float* out, float* ws)
{ decode_body<2>(emb, Wih, Whh, bih, bhh, Wout, bout, out, ws); }

__global__ __launch_bounds__(NTz, 2) void rnn_full(
    const float* emb, const float* Wih, const float* Whh, const float* bih,
    const float* bhh, const float* Wout, const float* bout, float* out, float* ws)
{ decode_body<3>(emb, Wih, Whh, bih, bhh, Wout, bout, out, ws); }

extern "C" void kernel_launch(void* const* d_in, const int* in_sizes, int n_in,
                              void* d_out, int out_size, void* d_ws, size_t ws_size,
                              hipStream_t stream) {
  (void)in_sizes; (void)n_in; (void)out_size;
  const float* enc  = (const float*)d_in[0];
  const float* emb  = (const float*)d_in[1];
  const float* Wih  = (const float*)d_in[2];
  const float* Whh  = (const float*)d_in[3];
  const float* bih  = (const float*)d_in[4];
  const float* bhh  = (const float*)d_in[5];
  const float* Wout = (const float*)d_in[6];
  const float* bout = (const float*)d_in[7];
  float* out = (float*)d_out;
  float* ws  = (float*)d_ws;

  (void)hipFuncSetAttribute((const void*)zz_nomv,
                            hipFuncAttributeMaxDynamicSharedMemorySize, L_TOTAL);
  (void)hipFuncSetAttribute((const void*)zz_nosm,
                            hipFuncAttributeMaxDynamicSharedMemorySize, L_TOTAL);
  (void)hipFuncSetAttribute((const void*)zz_nowr,
                            hipFuncAttributeMaxDynamicSharedMemorySize, L_TOTAL);
  (void)hipFuncSetAttribute((const void*)rnn_full,
                            hipFuncAttributeMaxDynamicSharedMemorySize, L_TOTAL);

  const size_t strideF = INST_B / 4;
  const bool ablate = ws_size >= (size_t)NINST * INST_B;

  if (ablate) {
    for (int i = 0; i < NINST; ++i)
      rnn_init<<<64, 512, 0, stream>>>(enc, ws + i * strideF);
    zz_nomv<<<Gz, NTz, L_TOTAL, stream>>>(emb, Wih, Whh, bih, bhh, Wout, bout, out, ws + 0 * strideF);
    zz_nosm<<<Gz, NTz, L_TOTAL, stream>>>(emb, Wih, Whh, bih, bhh, Wout, bout, out, ws + 1 * strideF);
    zz_nowr<<<Gz, NTz, L_TOTAL, stream>>>(emb, Wih, Whh, bih, bhh, Wout, bout, out, ws + 2 * strideF);
    rnn_full<<<Gz, NTz, L_TOTAL, stream>>>(emb, Wih, Whh, bih, bhh, Wout, bout, out, ws + 3 * strideF);
  } else {
    rnn_init<<<64, 512, 0, stream>>>(enc, ws);
    rnn_full<<<Gz, NTz, L_TOTAL, stream>>>(emb, Wih, Whh, bih, bhh, Wout, bout, out, ws);
  }
}

// Round 16
// 12008.051 us; speedup vs baseline: 4.2101x; 4.2101x over previous
//
#include <hip/hip_runtime.h>
#include <math.h>

#define Gz   250
#define NTz  512
#define Bz   32
#define Hz   512
#define Vz   32000
#define Tz   128
#define VBz  128
#define BHz  (Bz*Hz)
#define LBHz (2*BHz)
#define BTVz ((size_t)Bz*(size_t)Tz*(size_t)Vz)

// workspace byte offsets
#define WS_BAR  0         // unsigned[512]: grp[i] at [i*32], master at [256], gen at [257]
#define WS_ASUM 2048      // float[16][32]  (2KB)
#define WS_AMAX 4096      // ull[16][32]   (4KB)
#define WS_H    8192      // float[2 parity][2 layer][32][512]

// LDS byte offsets (dynamic)
#define L_HSA    0         // float[32][512] swizzled: h_L0 (resident across step)
#define L_HSB    65536     // float[32][512] swizzled: h_L1 (resident across step)
#define L_LOGITS 131072    // float[32*129]
#define L_SPART  131072    // overlay: float[16*32*8] (clobbers logits AFTER write_logp)
#define L_PMAX   147584    // ull[16*32]   (also tok_reduce redM scratch)
#define L_PSUM   151680    // float[16*32] (also tok_reduce redS scratch)
#define L_BIAS   156800    // float[16]
#define L_LOGZ   156864    // float[32]
#define L_TOK    156992    // int[32]
#define L_C      157120    // float[2][4][32]
#define L_TOTAL  158144

typedef unsigned long long ull;
typedef float f32x4 __attribute__((ext_vector_type(4)));
typedef unsigned long long ull2 __attribute__((ext_vector_type(2)));

__device__ __forceinline__ float sigmf(float x) { return 1.0f / (1.0f + expf(-x)); }

__device__ __forceinline__ ull bp8(const float* p) {   // coherent 8B load (MALL-direct)
  return __hip_atomic_load((const ull*)p, __ATOMIC_RELAXED, __HIP_MEMORY_SCOPE_AGENT);
}
__device__ __forceinline__ void cstore(float* p, float v) {  // MALL-direct 4B store
  __hip_atomic_store(p, v, __ATOMIC_RELAXED, __HIP_MEMORY_SCOPE_AGENT);
}
__device__ __forceinline__ ull packlm(float x, int v) {
  unsigned u = __float_as_uint(x);
  u = (u & 0x80000000u) ? ~u : (u | 0x80000000u);
  return ((ull)u << 32) | (unsigned)(Vz - 1 - v);   // lower v wins ties (np.argmax first-max)
}
__device__ __forceinline__ int hoff(int b, int k) { return (b << 9) + (k ^ ((b & 15) << 2)); }

// ALL-RELAXED grid barrier (proven correct R7..R15).
__device__ __forceinline__ void grid_barrier(unsigned* bar, int bid) {
  __syncthreads();
  if (threadIdx.x == 0) {
    unsigned* gen = bar + 257;
    unsigned g = __hip_atomic_load(gen, __ATOMIC_RELAXED, __HIP_MEMORY_SCOPE_AGENT);
    const int gi = bid & 7;
    const unsigned gsz = (unsigned)(Gz >> 3) + (((unsigned)gi < (Gz & 7u)) ? 1u : 0u);
    unsigned prev = __hip_atomic_fetch_add(&bar[gi * 32], 1u, __ATOMIC_RELAXED, __HIP_MEMORY_SCOPE_AGENT);
    if (prev == gsz - 1u) {
      __hip_atomic_store(&bar[gi * 32], 0u, __ATOMIC_RELAXED, __HIP_MEMORY_SCOPE_AGENT);
      asm volatile("s_waitcnt vmcnt(0)" ::: "memory");
      unsigned pm = __hip_atomic_fetch_add(&bar[256], 1u, __ATOMIC_RELAXED, __HIP_MEMORY_SCOPE_AGENT);
      if (pm == 7u) {
        __hip_atomic_store(&bar[256], 0u, __ATOMIC_RELAXED, __HIP_MEMORY_SCOPE_AGENT);
        asm volatile("s_waitcnt vmcnt(0)" ::: "memory");
        __hip_atomic_store(gen, g + 1u, __ATOMIC_RELAXED, __HIP_MEMORY_SCOPE_AGENT);
      }
    }
    while (__hip_atomic_load(gen, __ATOMIC_RELAXED, __HIP_MEMORY_SCOPE_AGENT) == g)
      __builtin_amdgcn_s_sleep(1);
  }
  __syncthreads();
}

// stage [32][512] floats via 16B coherent loads (sc1 = agent scope, MALL-direct):
// 8 iters x 512 threads x 16B; 4+4 loads batched in-flight, one vmcnt drain.
__device__ __forceinline__ void stage16(const float* __restrict__ src, float* lds, int tid) {
  const float* q0 = src + ((0 * NTz + tid) << 2);
  const float* q1 = src + ((1 * NTz + tid) << 2);
  const float* q2 = src + ((2 * NTz + tid) << 2);
  const float* q3 = src + ((3 * NTz + tid) << 2);
  const float* q4 = src + ((4 * NTz + tid) << 2);
  const float* q5 = src + ((5 * NTz + tid) << 2);
  const float* q6 = src + ((6 * NTz + tid) << 2);
  const float* q7 = src + ((7 * NTz + tid) << 2);
  f32x4 a0, a1, a2, a3, b0, b1, b2, b3;
  asm volatile(
      "global_load_dwordx4 %0, %4, off sc1\n\t"
      "global_load_dwordx4 %1, %5, off sc1\n\t"
      "global_load_dwordx4 %2, %6, off sc1\n\t"
      "global_load_dwordx4 %3, %7, off sc1"
      : "=&v"(a0), "=&v"(a1), "=&v"(a2), "=&v"(a3)
      : "v"(q0), "v"(q1), "v"(q2), "v"(q3) : "memory");
  asm volatile(
      "global_load_dwordx4 %0, %4, off sc1\n\t"
      "global_load_dwordx4 %1, %5, off sc1\n\t"
      "global_load_dwordx4 %2, %6, off sc1\n\t"
      "global_load_dwordx4 %3, %7, off sc1\n\t"
      "s_waitcnt vmcnt(0)"
      : "=&v"(b0), "=&v"(b1), "=&v"(b2), "=&v"(b3)
      : "v"(q4), "v"(q5), "v"(q6), "v"(q7) : "memory");
  #define ST16(IT, R) { int f = ((IT * NTz + tid) << 2); \
    *(f32x4*)(lds + hoff(f >> 9, f & 511)) = R; }
  ST16(0, a0) ST16(1, a1) ST16(2, a2) ST16(3, a3)
  ST16(4, b0) ST16(5, b1) ST16(6, b2) ST16(7, b3)
  #undef ST16
}

template<bool X_FROM_EMB>
__device__ __forceinline__ void lstm_phase(
    int tid, int hblk,
    const float* __restrict__ emb, const int* s_tok_,
    const float* xlds, const float* hlds,
    const float* __restrict__ Wih, const float* __restrict__ Whh,
    const float* __restrict__ bih, const float* __restrict__ bhh,
    float* s_part_, float* s_bias_, float* c_l,
    float* hdst)
{
  if (tid < 16) {
    int gate = tid >> 2, hl = tid & 3;
    int j = gate * Hz + (hblk << 2) + hl;
    s_bias_[tid] = bih[j] + bhh[j];
  }
  const int b = tid & 31, kq = (tid >> 5) & 7, rp = tid >> 8;
  const int k0 = kq * 64;
  const int swz = (b & 15) << 2;

  const float* wiA = Wih + (size_t)(2 * rp * Hz + (hblk << 2)) * Hz + k0;
  const float* whA = Whh + (size_t)(2 * rp * Hz + (hblk << 2)) * Hz + k0;

  const float* xbase; const float* hbase = hlds + (b << 9);
  if (X_FROM_EMB) xbase = emb + (size_t)s_tok_[b] * Hz + k0;
  else            xbase = xlds + (b << 9);

  float acc[8];
  #pragma unroll
  for (int r = 0; r < 8; ++r) acc[r] = 0.f;

  #pragma unroll 2
  for (int c = 0; c < 64; c += 4) {
    float x0, x1, x2, x3;
    if (X_FROM_EMB) {
      float4 xv = *(const float4*)(xbase + c);
      x0 = fmaxf(xv.x, 0.f); x1 = fmaxf(xv.y, 0.f);
      x2 = fmaxf(xv.z, 0.f); x3 = fmaxf(xv.w, 0.f);
    } else {
      float4 xv = *(const float4*)(xbase + ((k0 + c) ^ swz));
      x0 = xv.x; x1 = xv.y; x2 = xv.z; x3 = xv.w;
    }
    float4 hv = *(const float4*)(hbase + ((k0 + c) ^ swz));
    #pragma unroll
    for (int r = 0; r < 8; ++r) {
      const size_t off = (size_t)(r >> 2) * (Hz * Hz) + (size_t)(r & 3) * Hz + c;
      float4 wiv = *(const float4*)(wiA + off);
      float4 whv = *(const float4*)(whA + off);
      acc[r] += x0 * wiv.x + x1 * wiv.y + x2 * wiv.z + x3 * wiv.w
              + hv.x * whv.x + hv.y * whv.y + hv.z * whv.z + hv.w * whv.w;
    }
  }
  #pragma unroll
  for (int r = 0; r < 8; ++r)
    s_part_[((rp * 8 + r) * 32 + b) * 8 + kq] = acc[r];
  __syncthreads();
  {
    int row = tid >> 5, bb = tid & 31;
    float s = s_bias_[row];
    #pragma unroll
    for (int q = 0; q < 8; ++q) s += s_part_[(row * 32 + bb) * 8 + q];
    s_part_[(row * 32 + bb) * 8] = s;
  }
  __syncthreads();
  if (tid < 128) {
    int hl = tid >> 5, bb = tid & 31;
    float gi = s_part_[((0 * 4 + hl) * 32 + bb) * 8];
    float gf = s_part_[((1 * 4 + hl) * 32 + bb) * 8];
    float gg = s_part_[((2 * 4 + hl) * 32 + bb) * 8];
    float go = s_part_[((3 * 4 + hl) * 32 + bb) * 8];
    float c_old = c_l[hl * 32 + bb];
    float cn = sigmf(gf) * c_old + sigmf(gi) * tanhf(gg);
    c_l[hl * 32 + bb] = cn;
    cstore(hdst + bb * Hz + (hblk << 2) + hl, sigmf(go) * tanhf(cn));
  }
}

// vectorized token reduce over 16 buckets (384 coherent 16B requests/block)
__device__ __forceinline__ void tok_reduce2(int tid, const float* acc_sum, const ull* acc_max,
                                            float* redS, ull* redM, float* logZ, int* tok) {
  if (tid < 128) {
    int g = tid >> 3, b4 = (tid & 7) << 2;
    const float* p = acc_sum + (g << 5) + b4;
    f32x4 v;
    asm volatile("global_load_dwordx4 %0, %1, off sc1\n\ts_waitcnt vmcnt(0)"
                 : "=&v"(v) : "v"(p) : "memory");
    *(f32x4*)(redS + (g << 5) + b4) = v;
  } else if (tid < 384) {
    int u = tid - 128;
    int g = u >> 4, b2 = (u & 15) << 1;
    const ull* p = acc_max + (g << 5) + b2;
    ull2 m;
    asm volatile("global_load_dwordx4 %0, %1, off sc1\n\ts_waitcnt vmcnt(0)"
                 : "=&v"(m) : "v"(p) : "memory");
    *(ull2*)(redM + (g << 5) + b2) = m;
  }
  __syncthreads();
  if (tid < 32) {
    float s = 0.f; ull m = 0ull;
    #pragma unroll
    for (int g = 0; g < 16; ++g) {
      s += redS[(g << 5) + tid];
      ull x = redM[(g << 5) + tid]; m = x > m ? x : m;
    }
    logZ[tid] = logf(s);
    tok[tid] = (Vz - 1) - (int)(unsigned)(m & 0xFFFFFFFFull);
  }
  __syncthreads();
}

__device__ __forceinline__ void write_logp(int tid, int v0, int tstep,
                                           const float* logits_, const float* logZ_, float* out) {
  #pragma unroll
  for (int i = 0; i < 2; ++i) {
    int pos = ((i * NTz) + tid) * 4;
    int b = pos >> 7, v = pos & 127;
    float lz = logZ_[b];
    f32x4 rr;
    rr.x = logits_[b * 129 + v]     - lz;
    rr.y = logits_[b * 129 + v + 1] - lz;
    rr.z = logits_[b * 129 + v + 2] - lz;
    rr.w = logits_[b * 129 + v + 3] - lz;
    __builtin_nontemporal_store(rr,
        (f32x4*)(out + (size_t)b * ((size_t)Tz * Vz) + (size_t)tstep * Vz + v0 + v));
  }
}

__global__ void rnn_init(const float* __restrict__ enc, float* __restrict__ ws) {
  int i = blockIdx.x * blockDim.x + threadIdx.x;   // 32768 threads
  float* hs = (float*)((char*)ws + WS_H);
  if (i < LBHz) hs[i] = enc[i];
  if (i < 768) ((ull*)((char*)ws + WS_ASUM))[i] = 0ull;   // sum(2KB) + max(4KB)
  if (i < 512) ((unsigned*)ws)[i] = 0u;
}

#define WL(r, J) (*(const f32x4*)(wr##r + (((J + kq) & 7) << 2)))
#define P3J(J) { \
  const int kk = (kq << 5) + (((J + kq) & 7) << 2); \
  f32x4 h4 = *(const f32x4*)(hb + (kk ^ swz)); \
  a0 += h4 * w0##J; a1 += h4 * w1##J; a2 += h4 * w2##J; a3 += h4 * w3##J; }

__global__ __launch_bounds__(NTz)
__attribute__((amdgpu_waves_per_eu(2, 2)))
void rnn_decode(
    const float* __restrict__ emb,  const float* __restrict__ Wih,
    const float* __restrict__ Whh,  const float* __restrict__ bih,
    const float* __restrict__ bhh,  const float* __restrict__ Wout,
    const float* __restrict__ bout, float* __restrict__ out,
    float* __restrict__ ws)
{
  extern __shared__ char smem[];
  const int tid = threadIdx.x;
  const int bid = blockIdx.x;

  unsigned* bar  = (unsigned*)ws;
  float* acc_sum = (float*)((char*)ws + WS_ASUM);
  ull*   acc_max = (ull*)((char*)ws + WS_AMAX);
  float* hbufs   = (float*)((char*)ws + WS_H);

  float* hsA    = (float*)(smem + L_HSA);
  float* hsB    = (float*)(smem + L_HSB);
  float* logits = (float*)(smem + L_LOGITS);
  float* s_part = (float*)(smem + L_SPART);
  ull*   pmax   = (ull*)(smem + L_PMAX);
  float* psum   = (float*)(smem + L_PSUM);
  float* s_bias = (float*)(smem + L_BIAS);
  float* s_logZ = (float*)(smem + L_LOGZ);
  int*   s_tok  = (int*)(smem + L_TOK);
  float* s_c    = (float*)(smem + L_C);

  const int v0 = bid * VBz;
  if (tid < 256) s_c[tid] = 0.f;
  __syncthreads();

  //---- one-time: W_out slice into 32 NAMED registers ----------------------
  const int vg = tid >> 4, kq = tid & 15;
  f32x4 w00, w01, w02, w03, w04, w05, w06, w07;
  f32x4 w10, w11, w12, w13, w14, w15, w16, w17;
  f32x4 w20, w21, w22, w23, w24, w25, w26, w27;
  f32x4 w30, w31, w32, w33, w34, w35, w36, w37;
  {
    const float* wr0 = Wout + (size_t)(v0 + (vg << 2) + 0) * Hz + (kq << 5);
    const float* wr1 = Wout + (size_t)(v0 + (vg << 2) + 1) * Hz + (kq << 5);
    const float* wr2 = Wout + (size_t)(v0 + (vg << 2) + 2) * Hz + (kq << 5);
    const float* wr3 = Wout + (size_t)(v0 + (vg << 2) + 3) * Hz + (kq << 5);
    w00 = WL(0,0); w01 = WL(0,1); w02 = WL(0,2); w03 = WL(0,3);
    w04 = WL(0,4); w05 = WL(0,5); w06 = WL(0,6); w07 = WL(0,7);
    w10 = WL(1,0); w11 = WL(1,1); w12 = WL(1,2); w13 = WL(1,3);
    w14 = WL(1,4); w15 = WL(1,5); w16 = WL(1,6); w17 = WL(1,7);
    w20 = WL(2,0); w21 = WL(2,1); w22 = WL(2,2); w23 = WL(2,3);
    w24 = WL(2,4); w25 = WL(2,5); w26 = WL(2,6); w27 = WL(2,7);
    w30 = WL(3,0); w31 = WL(3,1); w32 = WL(3,2); w33 = WL(3,3);
    w34 = WL(3,4); w35 = WL(3,5); w36 = WL(3,6); w37 = WL(3,7);
  }

  //---- prologue: LSTM blocks stage initial resident tiles -----------------
  if (bid < 128) {
    stage16(hbufs, hsA, tid);          // h_L0(0)
    stage16(hbufs + BHz, hsB, tid);    // h_L1(0)
  }
  __syncthreads();

  for (int t = 0; t < Tz; ++t) {
    asm volatile("" : "+v"(w00),"+v"(w01),"+v"(w02),"+v"(w03),
                      "+v"(w04),"+v"(w05),"+v"(w06),"+v"(w07));
    asm volatile("" : "+v"(w10),"+v"(w11),"+v"(w12),"+v"(w13),
                      "+v"(w14),"+v"(w15),"+v"(w16),"+v"(w17));
    asm volatile("" : "+v"(w20),"+v"(w21),"+v"(w22),"+v"(w23),
                      "+v"(w24),"+v"(w25),"+v"(w26),"+v"(w27));
    asm volatile("" : "+v"(w30),"+v"(w31),"+v"(w32),"+v"(w33),
                      "+v"(w34),"+v"(w35),"+v"(w36),"+v"(w37));

    float* h_old = hbufs + (t & 1) * LBHz;
    float* h_new = hbufs + ((t + 1) & 1) * LBHz;

    //---- P1: token decode; logp(t-1); LSTM L0 (h from resident hsA) ----
    if (t == 0) {
      if (tid < 32) s_tok[tid] = 1;   // SOS
      __syncthreads();
    } else {
      tok_reduce2(tid, acc_sum, acc_max, psum, pmax, s_logZ, s_tok);
      write_logp(tid, v0, t - 1, logits, s_logZ, out);
      __syncthreads();
    }
    if (bid < 128)
      lstm_phase<true>(tid, bid, emb, s_tok, nullptr, hsA,
                       Wih, Whh, bih, bhh, s_part, s_bias, s_c, h_new);
    grid_barrier(bar, bid);

    //---- P2: stage fresh h_L0 -> hsA; LSTM L1 (h from resident hsB) ----
    if (bid < 128) {
      stage16(h_new, hsA, tid);
      __syncthreads();
      lstm_phase<false>(tid, bid, nullptr, nullptr, hsA, hsB,
                        Wih + (size_t)2048 * Hz, Whh + (size_t)2048 * Hz,
                        bih + 2048, bhh + 2048, s_part, s_bias, s_c + 128, h_new + BHz);
    } else if (bid == 128) {
      ull* zb = (ull*)acc_sum;              // contiguous 6KB: sums then maxes
      for (int u = tid; u < 768; u += NTz)
        __hip_atomic_store(&zb[u], 0ull, __ATOMIC_RELAXED, __HIP_MEMORY_SCOPE_AGENT);
    }
    grid_barrier(bar, bid);

    //---- P3: stage fresh h_L1 -> hsB; named-register matvec; partials ----
    stage16(h_new + BHz, hsB, tid);
    __syncthreads();
    {
      const float b_r0 = bout[v0 + (vg << 2)];
      const float b_r1 = bout[v0 + (vg << 2) + 1];
      const float b_r2 = bout[v0 + (vg << 2) + 2];
      const float b_r3 = bout[v0 + (vg << 2) + 3];
      #pragma unroll 2
      for (int b = 0; b < 32; ++b) {
        const float* hb = hsB + (b << 9);
        const int swz = (b & 15) << 2;
        f32x4 a0 = (f32x4)0.f, a1 = (f32x4)0.f, a2 = (f32x4)0.f, a3 = (f32x4)0.f;
        P3J(0) P3J(1) P3J(2) P3J(3) P3J(4) P3J(5) P3J(6) P3J(7)
        float s0 = (a0.x + a0.y) + (a0.z + a0.w);
        float s1 = (a1.x + a1.y) + (a1.z + a1.w);
        float s2 = (a2.x + a2.y) + (a2.z + a2.w);
        float s3 = (a3.x + a3.y) + (a3.z + a3.w);
        #pragma unroll
        for (int m = 1; m < 16; m <<= 1) {
          s0 += __shfl_xor(s0, m);
          s1 += __shfl_xor(s1, m);
          s2 += __shfl_xor(s2, m);
          s3 += __shfl_xor(s3, m);
        }
        if (kq == 0) {
          logits[b * 129 + (vg << 2)]     = s0 + b_r0;
          logits[b * 129 + (vg << 2) + 1] = s1 + b_r1;
          logits[b * 129 + (vg << 2) + 2] = s2 + b_r2;
          logits[b * 129 + (vg << 2) + 3] = s3 + b_r3;
        }
      }
    }
    __syncthreads();
    {
      const int b2 = tid & 31, ch = tid >> 5;   // 16 chunks x 8 vocab
      float m = -3.0e38f; int argv = 0; float s = 0.f;
      #pragma unroll
      for (int u = 0; u < 8; ++u) {
        int vl = ch * 8 + u;
        float x = logits[b2 * 129 + vl];
        s += expf(x);                            // offset-0 softmax: logits O(1), safe
        if (x > m) { m = x; argv = vl; }
      }
      pmax[ch * 32 + b2] = packlm(m, v0 + argv);
      psum[ch * 32 + b2] = s;
    }
    __syncthreads();
    if (tid < 32) {
      ull m = 0ull; float s = 0.f;
      #pragma unroll
      for (int ch = 0; ch < 16; ++ch) {
        ull x = pmax[ch * 32 + tid]; m = x > m ? x : m;
        s += psum[ch * 32 + tid];
      }
      atomicAdd(&acc_sum[((bid & 15) << 5) + tid], s);
      atomicMax(&acc_max[((bid & 15) << 5) + tid], m);
    }
    grid_barrier(bar, bid);
  }

  //---- epilogue: logp(T-1), hT, cT ----
  tok_reduce2(tid, acc_sum, acc_max, psum, pmax, s_logZ, s_tok);
  write_logp(tid, v0, Tz - 1, logits, s_logZ, out);
  if (bid >= 128 && bid < 144) {
    int f = (bid - 128) * 2048 + tid * 4;       // hT: 32768 floats from parity-0 buffer
    ull a = bp8(hbufs + f), b = bp8(hbufs + f + 2);
    *(ull*)(out + BTVz + f) = a;
    *(ull*)(out + BTVz + f + 2) = b;
  }
  if (bid < 128 && tid < 256) {
    int l = tid >> 7, hl = (tid >> 5) & 3, bb = tid & 31;
    out[BTVz + LBHz + (size_t)l * BHz + (size_t)bb * Hz + (bid << 2) + hl] =
        s_c[l * 128 + hl * 32 + bb];
  }
}

extern "C" void kernel_launch(void* const* d_in, const int* in_sizes, int n_in,
                              void* d_out, int out_size, void* d_ws, size_t ws_size,
                              hipStream_t stream) {
  (void)in_sizes; (void)n_in; (void)out_size; (void)ws_size;
  const float* enc  = (const float*)d_in[0];
  const float* emb  = (const float*)d_in[1];
  const float* Wih  = (const float*)d_in[2];
  const float* Whh  = (const float*)d_in[3];
  const float* bih  = (const float*)d_in[4];
  const float* bhh  = (const float*)d_in[5];
  const float* Wout = (const float*)d_in[6];
  const float* bout = (const float*)d_in[7];
  float* out = (float*)d_out;
  float* ws  = (float*)d_ws;

  (void)hipFuncSetAttribute((const void*)rnn_decode,
                            hipFuncAttributeMaxDynamicSharedMemorySize, L_TOTAL);
  rnn_init<<<64, 512, 0, stream>>>(enc, ws);
  rnn_decode<<<Gz, NTz, L_TOTAL, stream>>>(emb, Wih, Whh, bih, bhh, Wout, bout, out, ws);
}